// Round 1
// baseline (1273.234 us; speedup 1.0000x reference)
//
#include <hip/hip_runtime.h>

#define ROWS 32
#define NTH  256

// ---------------------------------------------------------------------------
// Pre-pass: w_hh [384,128] -> w_hhT [128,384] in workspace, so per-step LDS
// staging is a contiguous float4 copy.
// ---------------------------------------------------------------------------
__global__ void whh_transpose_kernel(const float* __restrict__ whh,
                                     float* __restrict__ whhT) {
    int idx = blockIdx.x * 256 + threadIdx.x;   // 0..49151
    if (idx < 384 * 128) {
        int k = idx / 384;
        int j = idx - k * 384;
        whhT[idx] = whh[j * 128 + k];
    }
}

// ---------------------------------------------------------------------------
// Encoder layer helper: [32,128] (LDS) @ W[128,128] + bias -> [32,128] (LDS)
// thread map: c = tid&127 (out col), g = tid>>7 (row half)
// ---------------------------------------------------------------------------
template<bool RELU>
__device__ __forceinline__ void mlp_layer(const float (*in)[132],
                                          const float* __restrict__ W,
                                          const float* __restrict__ bias,
                                          float (*outl)[132], int c, int g) {
    float acc[16];
    #pragma unroll
    for (int i = 0; i < 16; i++) acc[i] = 0.f;
    for (int k = 0; k < 128; k += 4) {
        float w0 = W[(k + 0) * 128 + c];
        float w1 = W[(k + 1) * 128 + c];
        float w2 = W[(k + 2) * 128 + c];
        float w3 = W[(k + 3) * 128 + c];
        #pragma unroll
        for (int i = 0; i < 16; i++) {
            const float4 xv = *(const float4*)&in[g * 16 + i][k];
            acc[i] = fmaf(xv.x, w0, fmaf(xv.y, w1, fmaf(xv.z, w2, fmaf(xv.w, w3, acc[i]))));
        }
    }
    const float bv = bias[c];
    #pragma unroll
    for (int i = 0; i < 16; i++) {
        float v = acc[i] + bv;
        outl[g * 16 + i][c] = RELU ? fmaxf(v, 0.f) : v;
    }
}

__device__ __forceinline__ float fast_sigmoid(float x) {
    return __builtin_amdgcn_rcpf(1.f + __expf(-x));
}
__device__ __forceinline__ float fast_tanh(float x) {
    // 1 - 2/(e^{2x}+1): safe at both infinities
    return fmaf(-2.f, __builtin_amdgcn_rcpf(__expf(2.f * x) + 1.f), 1.f);
}

// ---------------------------------------------------------------------------
// Fused encoder + 49-step GRU + decoder. One block per 32 batch rows.
// ---------------------------------------------------------------------------
template<bool USE_T>
__global__ __launch_bounds__(NTH, 1)
void gru_fused_kernel(const float* __restrict__ x,
                      const float* __restrict__ ew0, const float* __restrict__ eb0,
                      const float* __restrict__ ew1, const float* __restrict__ eb1,
                      const float* __restrict__ ew2, const float* __restrict__ eb2,
                      const float* __restrict__ w_ih, const float* __restrict__ w_hh,
                      const float* __restrict__ b_ih, const float* __restrict__ b_hh,
                      const float* __restrict__ dw0, const float* __restrict__ db0,
                      const float* __restrict__ dw1, const float* __restrict__ db1,
                      const float* __restrict__ whhT,
                      float* __restrict__ out) {
    __shared__ float hA[32][132];        // hidden state (padded stride)
    __shared__ float smemB[32 * 132];    // encoder ping buffer, then out/xprev/dw0
    __shared__ float wbuf[2][8 * 384];   // double-buffered w_hh^T chunk (8 k's)

    const int tid = threadIdx.x;
    const int b0  = blockIdx.x * ROWS;

    // ---------------- encoder: x -> hA ----------------
    {
        const int c = tid & 127;
        const int g = tid >> 7;
        float acc[16];
        #pragma unroll
        for (int i = 0; i < 16; i++) acc[i] = 0.f;
        for (int k = 0; k < 256; k += 4) {
            float w0 = ew0[(k + 0) * 128 + c];
            float w1 = ew0[(k + 1) * 128 + c];
            float w2 = ew0[(k + 2) * 128 + c];
            float w3 = ew0[(k + 3) * 128 + c];
            #pragma unroll
            for (int i = 0; i < 16; i++) {
                const float4 xv = *(const float4*)(x + (size_t)(b0 + g * 16 + i) * 256 + k);
                acc[i] = fmaf(xv.x, w0, fmaf(xv.y, w1, fmaf(xv.z, w2, fmaf(xv.w, w3, acc[i]))));
            }
        }
        float bv = eb0[c];
        #pragma unroll
        for (int i = 0; i < 16; i++) hA[g * 16 + i][c] = fmaxf(acc[i] + bv, 0.f);
        __syncthreads();
        mlp_layer<true>(hA, ew1, eb1, (float(*)[132])smemB, c, g);
        __syncthreads();
        mlp_layer<false>((float(*)[132])smemB, ew2, eb2, hA, c, g);
        __syncthreads();
    }

    // ---------------- GRU setup ----------------
    float* outb  = smemB;                 // [32][52]
    float* xprev = smemB + 32 * 52;       // [32]
    float* dw0s  = smemB + 32 * 52 + 32;  // [128*16]

    const int tj = tid & 63;
    const int tb = tid >> 6;              // wave id; rows = tb + 4*r

    float wih[6], bih[6], bhh[6];
    #pragma unroll
    for (int c2 = 0; c2 < 6; c2++) {
        int j = tj + 64 * c2;
        wih[c2] = w_ih[j];
        bih[c2] = b_ih[j];
        bhh[c2] = b_hh[j];
    }
    float dw1r[16], db0r[16];
    #pragma unroll
    for (int o = 0; o < 16; o++) { dw1r[o] = dw1[o]; db0r[o] = db0[o]; }
    const float db1r = db1[0];

    for (int e = tid; e < 2048; e += NTH) dw0s[e] = dw0[e];
    if (tid < 32) { outb[tid * 52] = 0.f; xprev[tid] = 0.f; }
    __syncthreads();

    auto stage = [&](int buf, int cc) {
        if (USE_T) {
            const float4* src = (const float4*)(whhT + cc * (8 * 384));
            float4* dst = (float4*)wbuf[buf];
            #pragma unroll
            for (int i = 0; i < 3; i++) dst[tid + NTH * i] = src[tid + NTH * i];
        } else {
            #pragma unroll
            for (int i = 0; i < 12; i++) {
                int e  = tid + NTH * i;      // < 3072
                int kk = e / 384;
                int j  = e - kk * 384;
                wbuf[buf][kk * 384 + j] = w_hh[j * 128 + cc * 8 + kk];
            }
        }
    };

    // ---------------- 49 recurrent steps ----------------
    for (int t = 0; t < 49; ++t) {
        float acc[8][6];
        #pragma unroll
        for (int r = 0; r < 8; r++)
            #pragma unroll
            for (int c2 = 0; c2 < 6; c2++) acc[r][c2] = 0.f;

        stage(0, 0);
        for (int cc = 0; cc < 16; ++cc) {
            __syncthreads();
            if (cc < 15) stage((cc + 1) & 1, cc + 1);
            const float* wb = wbuf[cc & 1];
            const int k0 = cc * 8;
            #pragma unroll
            for (int kk = 0; kk < 8; kk += 4) {
                float4 hv[8];
                #pragma unroll
                for (int r = 0; r < 8; r++)
                    hv[r] = *(const float4*)&hA[tb + 4 * r][k0 + kk];
                #pragma unroll
                for (int q = 0; q < 4; q++) {
                    float wv[6];
                    #pragma unroll
                    for (int c2 = 0; c2 < 6; c2++)
                        wv[c2] = wb[(kk + q) * 384 + tj + 64 * c2];
                    #pragma unroll
                    for (int r = 0; r < 8; r++) {
                        const float hq = q == 0 ? hv[r].x : q == 1 ? hv[r].y
                                        : q == 2 ? hv[r].z : hv[r].w;
                        #pragma unroll
                        for (int c2 = 0; c2 < 6; c2++)
                            acc[r][c2] = fmaf(hq, wv[c2], acc[r][c2]);
                    }
                }
            }
        }

        // gates + h update (each thread owns full {r,z,n} triples; wave-local rows)
        #pragma unroll
        for (int r = 0; r < 8; r++) {
            const int b = tb + 4 * r;
            const float xp = xprev[b];
            #pragma unroll
            for (int p = 0; p < 2; p++) {
                const int j0 = tj + 64 * p;
                float gr  = acc[r][p]     + bhh[p]     + fmaf(xp, wih[p],     bih[p]);
                float gz  = acc[r][p + 2] + bhh[p + 2] + fmaf(xp, wih[p + 2], bih[p + 2]);
                float ghn = acc[r][p + 4] + bhh[p + 4];
                float gxn = fmaf(xp, wih[p + 4], bih[p + 4]);
                float rg = fast_sigmoid(gr);
                float zg = fast_sigmoid(gz);
                float ng = fast_tanh(fmaf(rg, ghn, gxn));
                float hold = hA[b][j0];
                hA[b][j0] = fmaf(zg, hold - ng, ng);   // (1-z)n + z h
            }
        }
        __syncthreads();

        // decoder: hn @ dw0 (+db0, relu) @ dw1 (+db1) -> out column t+1
        {
            const int b  = tid >> 3;   // 0..31
            const int oo = tid & 7;    // k-slice
            float d[16];
            #pragma unroll
            for (int o = 0; o < 16; o++) d[o] = 0.f;
            #pragma unroll
            for (int kq = 0; kq < 16; kq += 4) {
                const int k = oo * 16 + kq;
                const float4 hv = *(const float4*)&hA[b][k];
                #pragma unroll
                for (int q = 0; q < 4; q++) {
                    const float hq = q == 0 ? hv.x : q == 1 ? hv.y : q == 2 ? hv.z : hv.w;
                    const float* wrow = dw0s + (k + q) * 16;
                    #pragma unroll
                    for (int o = 0; o < 16; o++) d[o] = fmaf(hq, wrow[o], d[o]);
                }
            }
            #pragma unroll
            for (int s = 1; s < 8; s <<= 1) {
                #pragma unroll
                for (int o = 0; o < 16; o++) d[o] += __shfl_xor(d[o], s, 64);
            }
            if (oo == 0) {
                float accv = db1r;
                #pragma unroll
                for (int o = 0; o < 16; o++)
                    accv = fmaf(fmaxf(d[o] + db0r[o], 0.f), dw1r[o], accv);
                outb[b * 52 + t + 1] = accv;
                xprev[b] = accv;
            }
        }
    }

    __syncthreads();
    // coalesced output write: [32 rows][50 cols], col 0 = 0
    for (int e = tid; e < 32 * 50; e += NTH) {
        int b = e / 50;
        int t = e - b * 50;
        out[(size_t)b0 * 50 + e] = outb[b * 52 + t];
    }
}

// ---------------------------------------------------------------------------
extern "C" void kernel_launch(void* const* d_in, const int* in_sizes, int n_in,
                              void* d_out, int out_size, void* d_ws, size_t ws_size,
                              hipStream_t stream) {
    const float* x   = (const float*)d_in[0];
    const float* ew0 = (const float*)d_in[1];
    const float* eb0 = (const float*)d_in[2];
    const float* ew1 = (const float*)d_in[3];
    const float* eb1 = (const float*)d_in[4];
    const float* ew2 = (const float*)d_in[5];
    const float* eb2 = (const float*)d_in[6];
    const float* wih = (const float*)d_in[7];
    const float* whh = (const float*)d_in[8];
    const float* bih = (const float*)d_in[9];
    const float* bhh = (const float*)d_in[10];
    const float* dw0 = (const float*)d_in[11];
    const float* db0 = (const float*)d_in[12];
    const float* dw1 = (const float*)d_in[13];
    const float* db1 = (const float*)d_in[14];
    float* out = (float*)d_out;

    const bool use_t = ws_size >= (size_t)(384 * 128 * sizeof(float));
    if (use_t) {
        float* whhT = (float*)d_ws;
        whh_transpose_kernel<<<192, 256, 0, stream>>>(whh, whhT);
        gru_fused_kernel<true><<<256, 256, 0, stream>>>(
            x, ew0, eb0, ew1, eb1, ew2, eb2, wih, whh, bih, bhh,
            dw0, db0, dw1, db1, whhT, out);
    } else {
        gru_fused_kernel<false><<<256, 256, 0, stream>>>(
            x, ew0, eb0, ew1, eb1, ew2, eb2, wih, whh, bih, bhh,
            dw0, db0, dw1, db1, nullptr, out);
    }
}

// Round 2
// 877.417 us; speedup vs baseline: 1.4511x; 1.4511x over previous
//
#include <hip/hip_runtime.h>

#define NTH 256

typedef __attribute__((ext_vector_type(8))) short short8;
typedef __attribute__((ext_vector_type(4))) float floatx4;

// ---- bf16 helpers (RN-even) ----
__device__ __forceinline__ short f2bf(float f) {
    unsigned u = __float_as_uint(f);
    u += 0x7FFF + ((u >> 16) & 1);
    return (short)(u >> 16);
}
__device__ __forceinline__ float bf2f(short s) {
    return __uint_as_float(((unsigned)(unsigned short)s) << 16);
}

__device__ __forceinline__ float fast_sigmoid(float x) {
    return __builtin_amdgcn_rcpf(1.f + __expf(-x));
}
__device__ __forceinline__ float fast_tanh(float x) {
    return fmaf(-2.f, __builtin_amdgcn_rcpf(__expf(2.f * x) + 1.f), 1.f);
}

// ---------------------------------------------------------------------------
// Encoder layer helper: [32,128] (LDS) @ W[128,128] + bias -> [32,128] (LDS)
// ---------------------------------------------------------------------------
template<bool RELU>
__device__ __forceinline__ void mlp_layer(const float (*in)[132],
                                          const float* __restrict__ W,
                                          const float* __restrict__ bias,
                                          float (*outl)[132], int c, int g) {
    float acc[16];
    #pragma unroll
    for (int i = 0; i < 16; i++) acc[i] = 0.f;
    for (int k = 0; k < 128; k += 4) {
        float w0 = W[(k + 0) * 128 + c];
        float w1 = W[(k + 1) * 128 + c];
        float w2 = W[(k + 2) * 128 + c];
        float w3 = W[(k + 3) * 128 + c];
        #pragma unroll
        for (int i = 0; i < 16; i++) {
            const float4 xv = *(const float4*)&in[g * 16 + i][k];
            acc[i] = fmaf(xv.x, w0, fmaf(xv.y, w1, fmaf(xv.z, w2, fmaf(xv.w, w3, acc[i]))));
        }
    }
    const float bv = bias[c];
    #pragma unroll
    for (int i = 0; i < 16; i++) {
        float v = acc[i] + bv;
        outl[g * 16 + i][c] = RELU ? fmaxf(v, 0.f) : v;
    }
}

// ---------------------------------------------------------------------------
// Fused encoder + 49-step GRU (bf16x3 MFMA) + decoder. 32 rows per block.
// ---------------------------------------------------------------------------
__global__ __launch_bounds__(NTH, 1)
void gru_fused_kernel(const float* __restrict__ x,
                      const float* __restrict__ ew0, const float* __restrict__ eb0,
                      const float* __restrict__ ew1, const float* __restrict__ eb1,
                      const float* __restrict__ ew2, const float* __restrict__ eb2,
                      const float* __restrict__ w_ih, const float* __restrict__ w_hh,
                      const float* __restrict__ b_ih, const float* __restrict__ b_hh,
                      const float* __restrict__ dw0, const float* __restrict__ db0,
                      const float* __restrict__ dw1, const float* __restrict__ db1,
                      float* __restrict__ out) {
    __shared__ float hA[32][132];                    // fp32 hidden (exact z*h term)
    __shared__ float smemB[32 * 132];                // encoder ping buffer
    __shared__ __align__(16) short h_hi[32][136];    // bf16 hi plane of h
    __shared__ __align__(16) short h_lo[32][136];    // bf16 lo plane of h
    __shared__ float outb[32][52];
    __shared__ float xprev_s[32];

    const int tid  = threadIdx.x;
    const int b0   = blockIdx.x * 32;
    const int lane = tid & 63;
    const int w    = tid >> 6;     // wave id 0..3 -> j-range [w*32, w*32+32)
    const int quad = lane >> 4;    // 0..3
    const int l15  = lane & 15;

    // ---------------- encoder: x -> hA ----------------
    {
        const int c = tid & 127;
        const int g = tid >> 7;
        float acc[16];
        #pragma unroll
        for (int i = 0; i < 16; i++) acc[i] = 0.f;
        for (int k = 0; k < 256; k += 4) {
            float w0 = ew0[(k + 0) * 128 + c];
            float w1 = ew0[(k + 1) * 128 + c];
            float w2 = ew0[(k + 2) * 128 + c];
            float w3 = ew0[(k + 3) * 128 + c];
            #pragma unroll
            for (int i = 0; i < 16; i++) {
                const float4 xv = *(const float4*)(x + (size_t)(b0 + g * 16 + i) * 256 + k);
                acc[i] = fmaf(xv.x, w0, fmaf(xv.y, w1, fmaf(xv.z, w2, fmaf(xv.w, w3, acc[i]))));
            }
        }
        float bv = eb0[c];
        #pragma unroll
        for (int i = 0; i < 16; i++) hA[g * 16 + i][c] = fmaxf(acc[i] + bv, 0.f);
        __syncthreads();
        mlp_layer<true>(hA, ew1, eb1, (float(*)[132])smemB, c, g);
        __syncthreads();
        mlp_layer<false>((float(*)[132])smemB, ew2, eb2, hA, c, g);
        __syncthreads();
    }

    // ---------------- persistent register weights ----------------
    // B-fragments of w_hh^T, bf16 hi/lo. Wave w covers gate cols
    // {g*128 + w*32 + nt*16 + l15}. B[k][n] = w_hh[n][k]; frag k = quad*8+e.
    short8 wbh[6][4], wbl[6][4];
    #pragma unroll
    for (int g = 0; g < 3; g++) {
        #pragma unroll
        for (int nt = 0; nt < 2; nt++) {
            const int n = g * 128 + w * 32 + nt * 16 + l15;
            const float* wrow = w_hh + n * 128;
            #pragma unroll
            for (int kt = 0; kt < 4; kt++) {
                const int kb = kt * 32 + quad * 8;
                const float4 f0 = *(const float4*)(wrow + kb);
                const float4 f1 = *(const float4*)(wrow + kb + 4);
                float fv[8] = {f0.x, f0.y, f0.z, f0.w, f1.x, f1.y, f1.z, f1.w};
                short8 hi, lo;
                #pragma unroll
                for (int e = 0; e < 8; e++) {
                    short h = f2bf(fv[e]);
                    hi[e] = h;
                    lo[e] = f2bf(fv[e] - bf2f(h));
                }
                wbh[g * 2 + nt][kt] = hi;
                wbl[g * 2 + nt][kt] = lo;
            }
        }
    }
    // decoder dw0 B-fragments (used by waves 0,1; computed by all, harmless)
    short8 dwh[4], dwl[4];
    #pragma unroll
    for (int kt = 0; kt < 4; kt++) {
        short8 hi, lo;
        #pragma unroll
        for (int e = 0; e < 8; e++) {
            float f = dw0[(kt * 32 + quad * 8 + e) * 16 + l15];
            short h = f2bf(f);
            hi[e] = h;
            lo[e] = f2bf(f - bf2f(h));
        }
        dwh[kt] = hi;
        dwl[kt] = lo;
    }
    // gate constants for this lane's 6 columns
    float wihc[6], bihc[6], bhhc[6];
    #pragma unroll
    for (int g = 0; g < 3; g++)
        #pragma unroll
        for (int nt = 0; nt < 2; nt++) {
            const int n = g * 128 + w * 32 + nt * 16 + l15;
            wihc[g * 2 + nt] = w_ih[n];
            bihc[g * 2 + nt] = b_ih[n];
            bhhc[g * 2 + nt] = b_hh[n];
        }
    const float db0r = db0[l15];
    const float dw1r = dw1[l15];
    const float db1r = db1[0];

    // ---------------- h -> bf16 hi/lo planes; init outb/xprev ----------------
    for (int i = tid; i < 32 * 128; i += NTH) {
        const int b = i >> 7, j = i & 127;
        const float f = hA[b][j];
        const short h = f2bf(f);
        h_hi[b][j] = h;
        h_lo[b][j] = f2bf(f - bf2f(h));
    }
    if (tid < 32) { outb[tid][0] = 0.f; xprev_s[tid] = 0.f; }
    __syncthreads();

    // A-fragments of current h (both M-tiles, all waves identical)
    short8 afh[2][4], afl[2][4];
    #pragma unroll
    for (int mt = 0; mt < 2; mt++)
        #pragma unroll
        for (int kt = 0; kt < 4; kt++) {
            afh[mt][kt] = *(const short8*)&h_hi[mt * 16 + l15][kt * 32 + quad * 8];
            afl[mt][kt] = *(const short8*)&h_lo[mt * 16 + l15][kt * 32 + quad * 8];
        }

    // ---------------- 49 recurrent steps ----------------
    for (int t = 0; t < 49; t++) {
        __syncthreads();   // prev-iter plane reads & xprev writes complete

        // gh = h @ w_hh^T via 3-pass bf16 MFMA; acc[mt][g*2+nt]
        floatx4 acc[2][6];
        #pragma unroll
        for (int mt = 0; mt < 2; mt++)
            #pragma unroll
            for (int ti = 0; ti < 6; ti++) acc[mt][ti] = (floatx4){0.f, 0.f, 0.f, 0.f};
        #pragma unroll
        for (int kt = 0; kt < 4; kt++)
            #pragma unroll
            for (int mt = 0; mt < 2; mt++)
                #pragma unroll
                for (int ti = 0; ti < 6; ti++) {
                    acc[mt][ti] = __builtin_amdgcn_mfma_f32_16x16x32_bf16(
                        afh[mt][kt], wbh[ti][kt], acc[mt][ti], 0, 0, 0);
                    acc[mt][ti] = __builtin_amdgcn_mfma_f32_16x16x32_bf16(
                        afh[mt][kt], wbl[ti][kt], acc[mt][ti], 0, 0, 0);
                    acc[mt][ti] = __builtin_amdgcn_mfma_f32_16x16x32_bf16(
                        afl[mt][kt], wbh[ti][kt], acc[mt][ti], 0, 0, 0);
                }

        // gates fully in C-layout registers; write hnew to hA + planes
        #pragma unroll
        for (int mt = 0; mt < 2; mt++) {
            #pragma unroll
            for (int reg = 0; reg < 4; reg++) {
                const int b = mt * 16 + quad * 4 + reg;
                const float xp = xprev_s[b];
                #pragma unroll
                for (int nt = 0; nt < 2; nt++) {
                    const int tr = nt, tz = 2 + nt, tn = 4 + nt;
                    float gr  = acc[mt][tr][reg] + bhhc[tr] + fmaf(xp, wihc[tr], bihc[tr]);
                    float gz  = acc[mt][tz][reg] + bhhc[tz] + fmaf(xp, wihc[tz], bihc[tz]);
                    float ghn = acc[mt][tn][reg] + bhhc[tn];
                    float gxn = fmaf(xp, wihc[tn], bihc[tn]);
                    float rg = fast_sigmoid(gr);
                    float zg = fast_sigmoid(gz);
                    float ng = fast_tanh(fmaf(rg, ghn, gxn));
                    const int j = w * 32 + nt * 16 + l15;
                    const float hold = hA[b][j];
                    const float hn = fmaf(zg, hold - ng, ng);
                    hA[b][j] = hn;
                    const short hs = f2bf(hn);
                    h_hi[b][j] = hs;
                    h_lo[b][j] = f2bf(hn - bf2f(hs));
                }
            }
        }
        __syncthreads();   // planes now hold h_{t+1}

        // read A-fragments of h_{t+1} (needed next step AND by decoder now)
        #pragma unroll
        for (int mt = 0; mt < 2; mt++)
            #pragma unroll
            for (int kt = 0; kt < 4; kt++) {
                afh[mt][kt] = *(const short8*)&h_hi[mt * 16 + l15][kt * 32 + quad * 8];
                afl[mt][kt] = *(const short8*)&h_lo[mt * 16 + l15][kt * 32 + quad * 8];
            }

        // decoder on waves 0,1: d = relu(h_{t+1} @ dw0 + db0); out = d @ dw1 + db1
        if (w < 2) {
            floatx4 dacc = (floatx4){0.f, 0.f, 0.f, 0.f};
            #pragma unroll
            for (int kt = 0; kt < 4; kt++) {
                dacc = __builtin_amdgcn_mfma_f32_16x16x32_bf16(afh[w][kt], dwh[kt], dacc, 0, 0, 0);
                dacc = __builtin_amdgcn_mfma_f32_16x16x32_bf16(afh[w][kt], dwl[kt], dacc, 0, 0, 0);
                dacc = __builtin_amdgcn_mfma_f32_16x16x32_bf16(afl[w][kt], dwh[kt], dacc, 0, 0, 0);
            }
            float v[4];
            #pragma unroll
            for (int reg = 0; reg < 4; reg++)
                v[reg] = fmaxf(dacc[reg] + db0r, 0.f) * dw1r;
            #pragma unroll
            for (int s = 1; s < 16; s <<= 1) {
                #pragma unroll
                for (int reg = 0; reg < 4; reg++)
                    v[reg] += __shfl_xor(v[reg], s, 64);
            }
            if (l15 == 0) {
                #pragma unroll
                for (int reg = 0; reg < 4; reg++) {
                    const int b = w * 16 + quad * 4 + reg;
                    const float o = v[reg] + db1r;
                    outb[b][t + 1] = o;
                    xprev_s[b] = o;
                }
            }
        }
    }

    __syncthreads();
    // coalesced output write: [32 rows][50 cols], col 0 = 0
    for (int e = tid; e < 32 * 50; e += NTH) {
        const int b = e / 50;
        const int t = e - b * 50;
        out[(size_t)b0 * 50 + e] = outb[b][t];
    }
}

// ---------------------------------------------------------------------------
extern "C" void kernel_launch(void* const* d_in, const int* in_sizes, int n_in,
                              void* d_out, int out_size, void* d_ws, size_t ws_size,
                              hipStream_t stream) {
    const float* x   = (const float*)d_in[0];
    const float* ew0 = (const float*)d_in[1];
    const float* eb0 = (const float*)d_in[2];
    const float* ew1 = (const float*)d_in[3];
    const float* eb1 = (const float*)d_in[4];
    const float* ew2 = (const float*)d_in[5];
    const float* eb2 = (const float*)d_in[6];
    const float* wih = (const float*)d_in[7];
    const float* whh = (const float*)d_in[8];
    const float* bih = (const float*)d_in[9];
    const float* bhh = (const float*)d_in[10];
    const float* dw0 = (const float*)d_in[11];
    const float* db0 = (const float*)d_in[12];
    const float* dw1 = (const float*)d_in[13];
    const float* db1 = (const float*)d_in[14];
    float* out = (float*)d_out;

    gru_fused_kernel<<<256, NTH, 0, stream>>>(
        x, ew0, eb0, ew1, eb1, ew2, eb2, wih, whh, bih, bhh,
        dw0, db0, dw1, db1, out);
}

// Round 3
// 267.489 us; speedup vs baseline: 4.7599x; 3.2802x over previous
//
#include <hip/hip_runtime.h>

#define NTH 512

typedef __attribute__((ext_vector_type(8))) short short8;
typedef __attribute__((ext_vector_type(4))) float floatx4;

// ---- bf16 helpers (RN-even) ----
__device__ __forceinline__ short f2bf(float f) {
    unsigned u = __float_as_uint(f);
    u += 0x7FFF + ((u >> 16) & 1);
    return (short)(u >> 16);
}
__device__ __forceinline__ float bf2f(short s) {
    return __uint_as_float(((unsigned)(unsigned short)s) << 16);
}

__device__ __forceinline__ float fast_sigmoid(float x) {
    return __builtin_amdgcn_rcpf(1.f + __expf(-x));
}
__device__ __forceinline__ float fast_tanh(float x) {
    return fmaf(-2.f, __builtin_amdgcn_rcpf(__expf(2.f * x) + 1.f), 1.f);
}

// ---------------------------------------------------------------------------
// Encoder layer: [32,128] (LDS) @ W[128,128] + bias -> [32,128] (LDS)
// 512 threads: c = tid&127 (out col), g = tid>>7 (row group of 8)
// ---------------------------------------------------------------------------
template<bool RELU>
__device__ __forceinline__ void mlp_layer(const float (*in)[132],
                                          const float* __restrict__ W,
                                          const float* __restrict__ bias,
                                          float (*outl)[132], int c, int g) {
    float acc[8];
    #pragma unroll
    for (int i = 0; i < 8; i++) acc[i] = 0.f;
    for (int k = 0; k < 128; k += 4) {
        float w0 = W[(k + 0) * 128 + c];
        float w1 = W[(k + 1) * 128 + c];
        float w2 = W[(k + 2) * 128 + c];
        float w3 = W[(k + 3) * 128 + c];
        #pragma unroll
        for (int i = 0; i < 8; i++) {
            const float4 xv = *(const float4*)&in[g * 8 + i][k];
            acc[i] = fmaf(xv.x, w0, fmaf(xv.y, w1, fmaf(xv.z, w2, fmaf(xv.w, w3, acc[i]))));
        }
    }
    const float bv = bias[c];
    #pragma unroll
    for (int i = 0; i < 8; i++) {
        float v = acc[i] + bv;
        outl[g * 8 + i][c] = RELU ? fmaxf(v, 0.f) : v;
    }
}

// ---------------------------------------------------------------------------
// Fused encoder + 49-step GRU (bf16x3 MFMA) + decoder. 32 rows per block,
// 8 waves; wave w owns gate cols {g*128 + w*16 + l15 : g<3} (full r/z/n triple
// per lane), both 16-row M-tiles.
// ---------------------------------------------------------------------------
__global__ __launch_bounds__(NTH, 2)
void gru_fused_kernel(const float* __restrict__ x,
                      const float* __restrict__ ew0, const float* __restrict__ eb0,
                      const float* __restrict__ ew1, const float* __restrict__ eb1,
                      const float* __restrict__ ew2, const float* __restrict__ eb2,
                      const float* __restrict__ w_ih, const float* __restrict__ w_hh,
                      const float* __restrict__ b_ih, const float* __restrict__ b_hh,
                      const float* __restrict__ dw0, const float* __restrict__ db0,
                      const float* __restrict__ dw1, const float* __restrict__ db1,
                      float* __restrict__ out) {
    __shared__ float hA[32][132];                    // encoder output staging only
    __shared__ float smemB[32 * 132];                // encoder ping buffer
    __shared__ __align__(16) short h_hi[32][136];    // bf16 hi plane of h
    __shared__ __align__(16) short h_lo[32][136];    // bf16 lo plane of h
    __shared__ float outb[32][52];
    __shared__ float xprev_s[32];

    const int tid  = threadIdx.x;
    const int b0   = blockIdx.x * 32;
    const int lane = tid & 63;
    const int w    = tid >> 6;     // wave 0..7
    const int quad = lane >> 4;
    const int l15  = lane & 15;
    const int jcol = w * 16 + l15; // this lane's hidden col (per gate)

    // ---------------- encoder: x -> hA ----------------
    {
        const int c = tid & 127;
        const int g = tid >> 7;    // 0..3, 8 rows each
        float acc[8];
        #pragma unroll
        for (int i = 0; i < 8; i++) acc[i] = 0.f;
        for (int k = 0; k < 256; k += 4) {
            float w0 = ew0[(k + 0) * 128 + c];
            float w1 = ew0[(k + 1) * 128 + c];
            float w2 = ew0[(k + 2) * 128 + c];
            float w3 = ew0[(k + 3) * 128 + c];
            #pragma unroll
            for (int i = 0; i < 8; i++) {
                const float4 xv = *(const float4*)(x + (size_t)(b0 + g * 8 + i) * 256 + k);
                acc[i] = fmaf(xv.x, w0, fmaf(xv.y, w1, fmaf(xv.z, w2, fmaf(xv.w, w3, acc[i]))));
            }
        }
        float bv = eb0[c];
        #pragma unroll
        for (int i = 0; i < 8; i++) hA[g * 8 + i][c] = fmaxf(acc[i] + bv, 0.f);
        __syncthreads();
        mlp_layer<true>(hA, ew1, eb1, (float(*)[132])smemB, c, g);
        __syncthreads();
        mlp_layer<false>((float(*)[132])smemB, ew2, eb2, hA, c, g);
        __syncthreads();
    }

    // ---------------- persistent register weights ----------------
    // B-frag of w_hh^T for gate g: B[k][n], n = g*128 + jcol, k = kt*32+quad*8+e
    short8 wbh[3][4], wbl[3][4];
    #pragma unroll
    for (int g = 0; g < 3; g++) {
        const float* wrow = w_hh + (g * 128 + jcol) * 128;
        #pragma unroll
        for (int kt = 0; kt < 4; kt++) {
            const int kb = kt * 32 + quad * 8;
            const float4 f0 = *(const float4*)(wrow + kb);
            const float4 f1 = *(const float4*)(wrow + kb + 4);
            float fv[8] = {f0.x, f0.y, f0.z, f0.w, f1.x, f1.y, f1.z, f1.w};
            short8 hi, lo;
            #pragma unroll
            for (int e = 0; e < 8; e++) {
                short h = f2bf(fv[e]);
                hi[e] = h;
                lo[e] = f2bf(fv[e] - bf2f(h));
            }
            wbh[g][kt] = hi;
            wbl[g][kt] = lo;
        }
    }
    // decoder dw0 B-frags
    short8 dwh[4], dwl[4];
    #pragma unroll
    for (int kt = 0; kt < 4; kt++) {
        short8 hi, lo;
        #pragma unroll
        for (int e = 0; e < 8; e++) {
            float f = dw0[(kt * 32 + quad * 8 + e) * 16 + l15];
            short h = f2bf(f);
            hi[e] = h;
            lo[e] = f2bf(f - bf2f(h));
        }
        dwh[kt] = hi;
        dwl[kt] = lo;
    }
    // gate constants for this lane's column (3 gates)
    float wihc[3], bihc[3], bhhc[3];
    #pragma unroll
    for (int g = 0; g < 3; g++) {
        const int n = g * 128 + jcol;
        wihc[g] = w_ih[n];
        bihc[g] = b_ih[n];
        bhhc[g] = b_hh[n];
    }
    const float db0r = db0[l15];
    const float dw1r = dw1[l15];
    const float db1r = db1[0];

    // ---------------- init planes + lane-private fp32 h ----------------
    for (int i = tid; i < 32 * 128; i += NTH) {
        const int b = i >> 7, j = i & 127;
        const float f = hA[b][j];
        const short h = f2bf(f);
        h_hi[b][j] = h;
        h_lo[b][j] = f2bf(f - bf2f(h));
    }
    if (tid < 32) { outb[tid][0] = 0.f; xprev_s[tid] = 0.f; }
    __syncthreads();
    float hold[8];   // fp32 h at (b = mt*16+quad*4+reg, jcol) — lane-private
    #pragma unroll
    for (int mt = 0; mt < 2; mt++)
        #pragma unroll
        for (int reg = 0; reg < 4; reg++)
            hold[mt * 4 + reg] = hA[mt * 16 + quad * 4 + reg][jcol];

    // ---------------- 49 recurrent steps ----------------
    for (int t = 0; t < 49; t++) {
        // gh = h @ w_hh^T (3-pass bf16), A-frags loaded per-kt
        floatx4 acc[2][3];
        #pragma unroll
        for (int mt = 0; mt < 2; mt++)
            #pragma unroll
            for (int g = 0; g < 3; g++) acc[mt][g] = (floatx4){0.f, 0.f, 0.f, 0.f};
        #pragma unroll
        for (int kt = 0; kt < 4; kt++) {
            const int kb = kt * 32 + quad * 8;
            const short8 ah0 = *(const short8*)&h_hi[l15][kb];
            const short8 al0 = *(const short8*)&h_lo[l15][kb];
            const short8 ah1 = *(const short8*)&h_hi[16 + l15][kb];
            const short8 al1 = *(const short8*)&h_lo[16 + l15][kb];
            #pragma unroll
            for (int g = 0; g < 3; g++) {
                acc[0][g] = __builtin_amdgcn_mfma_f32_16x16x32_bf16(ah0, wbh[g][kt], acc[0][g], 0, 0, 0);
                acc[0][g] = __builtin_amdgcn_mfma_f32_16x16x32_bf16(ah0, wbl[g][kt], acc[0][g], 0, 0, 0);
                acc[0][g] = __builtin_amdgcn_mfma_f32_16x16x32_bf16(al0, wbh[g][kt], acc[0][g], 0, 0, 0);
                acc[1][g] = __builtin_amdgcn_mfma_f32_16x16x32_bf16(ah1, wbh[g][kt], acc[1][g], 0, 0, 0);
                acc[1][g] = __builtin_amdgcn_mfma_f32_16x16x32_bf16(ah1, wbl[g][kt], acc[1][g], 0, 0, 0);
                acc[1][g] = __builtin_amdgcn_mfma_f32_16x16x32_bf16(al1, wbh[g][kt], acc[1][g], 0, 0, 0);
            }
        }
        __syncthreads();   // all plane reads (h_t) done; xprev_s from prev decoder visible

        // gates + h update; write h_{t+1} planes
        #pragma unroll
        for (int mt = 0; mt < 2; mt++) {
            #pragma unroll
            for (int reg = 0; reg < 4; reg++) {
                const int b = mt * 16 + quad * 4 + reg;
                const float xp = xprev_s[b];
                float gr  = acc[mt][0][reg] + bhhc[0] + fmaf(xp, wihc[0], bihc[0]);
                float gz  = acc[mt][1][reg] + bhhc[1] + fmaf(xp, wihc[1], bihc[1]);
                float ghn = acc[mt][2][reg] + bhhc[2];
                float gxn = fmaf(xp, wihc[2], bihc[2]);
                float rg = fast_sigmoid(gr);
                float zg = fast_sigmoid(gz);
                float ng = fast_tanh(fmaf(rg, ghn, gxn));
                const float hn = fmaf(zg, hold[mt * 4 + reg] - ng, ng);
                hold[mt * 4 + reg] = hn;
                const short hs = f2bf(hn);
                h_hi[b][jcol] = hs;
                h_lo[b][jcol] = f2bf(hn - bf2f(hs));
            }
        }
        __syncthreads();   // planes now hold h_{t+1}

        // decoder on waves 0,1 (mt = w): out_{t+1} = relu(h@dw0+db0)@dw1+db1
        if (w < 2) {
            floatx4 dacc = (floatx4){0.f, 0.f, 0.f, 0.f};
            #pragma unroll
            for (int kt = 0; kt < 4; kt++) {
                const int kb = kt * 32 + quad * 8;
                const short8 ah = *(const short8*)&h_hi[w * 16 + l15][kb];
                const short8 al = *(const short8*)&h_lo[w * 16 + l15][kb];
                dacc = __builtin_amdgcn_mfma_f32_16x16x32_bf16(ah, dwh[kt], dacc, 0, 0, 0);
                dacc = __builtin_amdgcn_mfma_f32_16x16x32_bf16(ah, dwl[kt], dacc, 0, 0, 0);
                dacc = __builtin_amdgcn_mfma_f32_16x16x32_bf16(al, dwh[kt], dacc, 0, 0, 0);
            }
            float v[4];
            #pragma unroll
            for (int reg = 0; reg < 4; reg++)
                v[reg] = fmaxf(dacc[reg] + db0r, 0.f) * dw1r;
            #pragma unroll
            for (int s = 1; s < 16; s <<= 1) {
                #pragma unroll
                for (int reg = 0; reg < 4; reg++)
                    v[reg] += __shfl_xor(v[reg], s, 64);
            }
            if (l15 == 0) {
                #pragma unroll
                for (int reg = 0; reg < 4; reg++) {
                    const int b = w * 16 + quad * 4 + reg;
                    const float o = v[reg] + db1r;
                    outb[b][t + 1] = o;
                    xprev_s[b] = o;
                }
            }
        }
    }

    __syncthreads();
    // coalesced output write: [32 rows][50 cols], col 0 = 0
    for (int e = tid; e < 32 * 50; e += NTH) {
        const int b = e / 50;
        const int t = e - b * 50;
        out[(size_t)b0 * 50 + e] = outb[b][t];
    }
}

// ---------------------------------------------------------------------------
extern "C" void kernel_launch(void* const* d_in, const int* in_sizes, int n_in,
                              void* d_out, int out_size, void* d_ws, size_t ws_size,
                              hipStream_t stream) {
    const float* x   = (const float*)d_in[0];
    const float* ew0 = (const float*)d_in[1];
    const float* eb0 = (const float*)d_in[2];
    const float* ew1 = (const float*)d_in[3];
    const float* eb1 = (const float*)d_in[4];
    const float* ew2 = (const float*)d_in[5];
    const float* eb2 = (const float*)d_in[6];
    const float* wih = (const float*)d_in[7];
    const float* whh = (const float*)d_in[8];
    const float* bih = (const float*)d_in[9];
    const float* bhh = (const float*)d_in[10];
    const float* dw0 = (const float*)d_in[11];
    const float* db0 = (const float*)d_in[12];
    const float* dw1 = (const float*)d_in[13];
    const float* db1 = (const float*)d_in[14];
    float* out = (float*)d_out;

    gru_fused_kernel<<<256, NTH, 0, stream>>>(
        x, ew0, eb0, ew1, eb1, ew2, eb2, wih, whh, bih, bhh,
        dw0, db0, dw1, db1, out);
}

// Round 4
// 255.390 us; speedup vs baseline: 4.9855x; 1.0474x over previous
//
#include <hip/hip_runtime.h>

#define NTH 512

typedef __attribute__((ext_vector_type(8))) short short8;
typedef __attribute__((ext_vector_type(4))) float floatx4;

// ---- bf16 helpers ----
__device__ __forceinline__ short f2bf(float f) {            // RN-even
    unsigned u = __float_as_uint(f);
    u += 0x7FFF + ((u >> 16) & 1);
    return (short)(u >> 16);
}
__device__ __forceinline__ short f2bf_trunc(float f) {      // truncate (lo plane)
    return (short)(__float_as_uint(f) >> 16);
}
__device__ __forceinline__ float bf2f(short s) {
    return __uint_as_float(((unsigned)(unsigned short)s) << 16);
}

__device__ __forceinline__ float fast_sigmoid(float x) {
    return __builtin_amdgcn_rcpf(1.f + __expf(-x));
}
__device__ __forceinline__ float fast_tanh(float x) {
    return fmaf(-2.f, __builtin_amdgcn_rcpf(__expf(2.f * x) + 1.f), 1.f);
}

// ---------------------------------------------------------------------------
// Encoder layer: [32,128] (LDS) @ W[128,128] + bias -> [32,128] (LDS)
// 512 threads: c = tid&127 (out col), g = tid>>7 (row group of 8)
// ---------------------------------------------------------------------------
template<bool RELU>
__device__ __forceinline__ void mlp_layer(const float (*in)[132],
                                          const float* __restrict__ W,
                                          const float* __restrict__ bias,
                                          float (*outl)[132], int c, int g) {
    float acc[8];
    #pragma unroll
    for (int i = 0; i < 8; i++) acc[i] = 0.f;
    for (int k = 0; k < 128; k += 4) {
        float w0 = W[(k + 0) * 128 + c];
        float w1 = W[(k + 1) * 128 + c];
        float w2 = W[(k + 2) * 128 + c];
        float w3 = W[(k + 3) * 128 + c];
        #pragma unroll
        for (int i = 0; i < 8; i++) {
            const float4 xv = *(const float4*)&in[g * 8 + i][k];
            acc[i] = fmaf(xv.x, w0, fmaf(xv.y, w1, fmaf(xv.z, w2, fmaf(xv.w, w3, acc[i]))));
        }
    }
    const float bv = bias[c];
    #pragma unroll
    for (int i = 0; i < 8; i++) {
        float v = acc[i] + bv;
        outl[g * 8 + i][c] = RELU ? fmaxf(v, 0.f) : v;
    }
}

// ---------------------------------------------------------------------------
// Fused encoder + 50-iter GRU (bf16x3 MFMA) + overlapped decoder.
// 32 rows/block, 8 waves; wave w owns gate cols {g*128 + w*16 + l15}.
// Double-buffered bf16 hi/lo planes; decoder runs concurrently with the
// recurrent MFMA in phase1 (both read the same h_t planes).
// ---------------------------------------------------------------------------
__global__ __launch_bounds__(NTH, 1) __attribute__((amdgpu_waves_per_eu(2)))
void gru_fused_kernel(const float* __restrict__ x,
                      const float* __restrict__ ew0, const float* __restrict__ eb0,
                      const float* __restrict__ ew1, const float* __restrict__ eb1,
                      const float* __restrict__ ew2, const float* __restrict__ eb2,
                      const float* __restrict__ w_ih, const float* __restrict__ w_hh,
                      const float* __restrict__ b_ih, const float* __restrict__ b_hh,
                      const float* __restrict__ dw0, const float* __restrict__ db0,
                      const float* __restrict__ dw1, const float* __restrict__ db1,
                      float* __restrict__ out) {
    __shared__ float hA[32][132];                    // encoder staging
    __shared__ float smemB[32 * 132];                // encoder ping buffer
    __shared__ __align__(16) short h_hi[2][32][136]; // bf16 hi planes (dbuf)
    __shared__ __align__(16) short h_lo[2][32][136]; // bf16 lo planes (dbuf)
    __shared__ float outb[32][52];
    __shared__ float xprev_s[32];

    const int tid  = threadIdx.x;
    const int b0   = blockIdx.x * 32;
    const int lane = tid & 63;
    const int w    = tid >> 6;     // wave 0..7
    const int quad = lane >> 4;
    const int l15  = lane & 15;
    const int jcol = w * 16 + l15; // this lane's hidden col (per gate)

    // ---------------- encoder: x -> hA ----------------
    {
        const int c = tid & 127;
        const int g = tid >> 7;    // 0..3, 8 rows each
        float acc[8];
        #pragma unroll
        for (int i = 0; i < 8; i++) acc[i] = 0.f;
        for (int k = 0; k < 256; k += 4) {
            float w0 = ew0[(k + 0) * 128 + c];
            float w1 = ew0[(k + 1) * 128 + c];
            float w2 = ew0[(k + 2) * 128 + c];
            float w3 = ew0[(k + 3) * 128 + c];
            #pragma unroll
            for (int i = 0; i < 8; i++) {
                const float4 xv = *(const float4*)(x + (size_t)(b0 + g * 8 + i) * 256 + k);
                acc[i] = fmaf(xv.x, w0, fmaf(xv.y, w1, fmaf(xv.z, w2, fmaf(xv.w, w3, acc[i]))));
            }
        }
        float bv = eb0[c];
        #pragma unroll
        for (int i = 0; i < 8; i++) hA[g * 8 + i][c] = fmaxf(acc[i] + bv, 0.f);
        __syncthreads();
        mlp_layer<true>(hA, ew1, eb1, (float(*)[132])smemB, c, g);
        __syncthreads();
        mlp_layer<false>((float(*)[132])smemB, ew2, eb2, hA, c, g);
        __syncthreads();
    }

    // ---------------- persistent register weights ----------------
    short8 wbh[3][4], wbl[3][4];
    #pragma unroll
    for (int g = 0; g < 3; g++) {
        const float* wrow = w_hh + (g * 128 + jcol) * 128;
        #pragma unroll
        for (int kt = 0; kt < 4; kt++) {
            const int kb = kt * 32 + quad * 8;
            const float4 f0 = *(const float4*)(wrow + kb);
            const float4 f1 = *(const float4*)(wrow + kb + 4);
            float fv[8] = {f0.x, f0.y, f0.z, f0.w, f1.x, f1.y, f1.z, f1.w};
            short8 hi, lo;
            #pragma unroll
            for (int e = 0; e < 8; e++) {
                short h = f2bf(fv[e]);
                hi[e] = h;
                lo[e] = f2bf_trunc(fv[e] - bf2f(h));
            }
            wbh[g][kt] = hi;
            wbl[g][kt] = lo;
        }
    }
    short8 dwh[4], dwl[4];
    #pragma unroll
    for (int kt = 0; kt < 4; kt++) {
        short8 hi, lo;
        #pragma unroll
        for (int e = 0; e < 8; e++) {
            float f = dw0[(kt * 32 + quad * 8 + e) * 16 + l15];
            short h = f2bf(f);
            hi[e] = h;
            lo[e] = f2bf_trunc(f - bf2f(h));
        }
        dwh[kt] = hi;
        dwl[kt] = lo;
    }
    // gate constants: folded biases for r,z; split for n
    float wihc0 = w_ih[jcol],       bs_r  = b_ih[jcol] + b_hh[jcol];
    float wihc1 = w_ih[128 + jcol], bs_z  = b_ih[128 + jcol] + b_hh[128 + jcol];
    float wihc2 = w_ih[256 + jcol], bih_n = b_ih[256 + jcol], bhh_n = b_hh[256 + jcol];
    const float db0r = db0[l15];
    const float dw1r = dw1[l15];
    const float db1r = db1[0];

    // ---------------- init planes[0] + lane-private fp32 h ----------------
    for (int i = tid; i < 32 * 128; i += NTH) {
        const int b = i >> 7, j = i & 127;
        const float f = hA[b][j];
        const short h = f2bf(f);
        h_hi[0][b][j] = h;
        h_lo[0][b][j] = f2bf_trunc(f - bf2f(h));
    }
    if (tid < 32) { outb[tid][0] = 0.f; xprev_s[tid] = 0.f; }
    float hold[8];
    #pragma unroll
    for (int mt = 0; mt < 2; mt++)
        #pragma unroll
        for (int reg = 0; reg < 4; reg++)
            hold[mt * 4 + reg] = hA[mt * 16 + quad * 4 + reg][jcol];
    __syncthreads();

    // ---------------- 50 iterations: t computes dec(h_t) and h_{t+1} -------
    for (int t = 0; t <= 49; t++) {
        const int cur = t & 1, nxt = cur ^ 1;

        // phase1: gh = h_t @ w_hh^T (all waves) || decoder dec(h_t) (waves 0,1)
        floatx4 acc[2][3];
        #pragma unroll
        for (int mt = 0; mt < 2; mt++)
            #pragma unroll
            for (int g = 0; g < 3; g++) acc[mt][g] = (floatx4){0.f, 0.f, 0.f, 0.f};
        floatx4 dacc = (floatx4){0.f, 0.f, 0.f, 0.f};

        #pragma unroll
        for (int kt = 0; kt < 4; kt++) {
            const int kb = kt * 32 + quad * 8;
            const short8 ah0 = *(const short8*)&h_hi[cur][l15][kb];
            const short8 al0 = *(const short8*)&h_lo[cur][l15][kb];
            const short8 ah1 = *(const short8*)&h_hi[cur][16 + l15][kb];
            const short8 al1 = *(const short8*)&h_lo[cur][16 + l15][kb];
            if (t < 49) {
                #pragma unroll
                for (int g = 0; g < 3; g++) {
                    acc[0][g] = __builtin_amdgcn_mfma_f32_16x16x32_bf16(ah0, wbh[g][kt], acc[0][g], 0, 0, 0);
                    acc[0][g] = __builtin_amdgcn_mfma_f32_16x16x32_bf16(ah0, wbl[g][kt], acc[0][g], 0, 0, 0);
                    acc[0][g] = __builtin_amdgcn_mfma_f32_16x16x32_bf16(al0, wbh[g][kt], acc[0][g], 0, 0, 0);
                    acc[1][g] = __builtin_amdgcn_mfma_f32_16x16x32_bf16(ah1, wbh[g][kt], acc[1][g], 0, 0, 0);
                    acc[1][g] = __builtin_amdgcn_mfma_f32_16x16x32_bf16(ah1, wbl[g][kt], acc[1][g], 0, 0, 0);
                    acc[1][g] = __builtin_amdgcn_mfma_f32_16x16x32_bf16(al1, wbh[g][kt], acc[1][g], 0, 0, 0);
                }
            }
            if (t > 0 && w < 2) {
                const short8 ahd = w ? ah1 : ah0;
                const short8 ald = w ? al1 : al0;
                dacc = __builtin_amdgcn_mfma_f32_16x16x32_bf16(ahd, dwh[kt], dacc, 0, 0, 0);
                dacc = __builtin_amdgcn_mfma_f32_16x16x32_bf16(ahd, dwl[kt], dacc, 0, 0, 0);
                dacc = __builtin_amdgcn_mfma_f32_16x16x32_bf16(ald, dwh[kt], dacc, 0, 0, 0);
            }
        }

        if (t > 0 && w < 2) {
            float v[4];
            #pragma unroll
            for (int reg = 0; reg < 4; reg++)
                v[reg] = fmaxf(dacc[reg] + db0r, 0.f) * dw1r;
            #pragma unroll
            for (int s = 1; s < 16; s <<= 1) {
                #pragma unroll
                for (int reg = 0; reg < 4; reg++)
                    v[reg] += __shfl_xor(v[reg], s, 64);
            }
            if (l15 == 0) {
                #pragma unroll
                for (int reg = 0; reg < 4; reg++) {
                    const int b = w * 16 + quad * 4 + reg;
                    const float o = v[reg] + db1r;
                    outb[b][t] = o;       // out column t = dec(h_t)
                    xprev_s[b] = o;       // x input for gates this iteration
                }
            }
        }
        __syncthreads();   // xprev_s visible; h_t plane reads complete

        // phase2: gates -> h_{t+1} into planes[nxt]
        if (t < 49) {
            #pragma unroll
            for (int mt = 0; mt < 2; mt++) {
                #pragma unroll
                for (int reg = 0; reg < 4; reg++) {
                    const int b = mt * 16 + quad * 4 + reg;
                    const float xp = xprev_s[b];
                    float gr  = fmaf(xp, wihc0, acc[mt][0][reg] + bs_r);
                    float gz  = fmaf(xp, wihc1, acc[mt][1][reg] + bs_z);
                    float ghn = acc[mt][2][reg] + bhh_n;
                    float gxn = fmaf(xp, wihc2, bih_n);
                    float rg = fast_sigmoid(gr);
                    float zg = fast_sigmoid(gz);
                    float ng = fast_tanh(fmaf(rg, ghn, gxn));
                    const float hn = fmaf(zg, hold[mt * 4 + reg] - ng, ng);
                    hold[mt * 4 + reg] = hn;
                    const short hs = f2bf(hn);
                    h_hi[nxt][b][jcol] = hs;
                    h_lo[nxt][b][jcol] = f2bf_trunc(hn - bf2f(hs));
                }
            }
            __syncthreads();   // planes[nxt] = h_{t+1} complete
        }
    }

    __syncthreads();
    // coalesced output write: [32 rows][50 cols], col 0 = 0
    for (int e = tid; e < 32 * 50; e += NTH) {
        const int b = e / 50;
        const int t = e - b * 50;
        out[(size_t)b0 * 50 + e] = outb[b][t];
    }
}

// ---------------------------------------------------------------------------
extern "C" void kernel_launch(void* const* d_in, const int* in_sizes, int n_in,
                              void* d_out, int out_size, void* d_ws, size_t ws_size,
                              hipStream_t stream) {
    const float* x   = (const float*)d_in[0];
    const float* ew0 = (const float*)d_in[1];
    const float* eb0 = (const float*)d_in[2];
    const float* ew1 = (const float*)d_in[3];
    const float* eb1 = (const float*)d_in[4];
    const float* ew2 = (const float*)d_in[5];
    const float* eb2 = (const float*)d_in[6];
    const float* wih = (const float*)d_in[7];
    const float* whh = (const float*)d_in[8];
    const float* bih = (const float*)d_in[9];
    const float* bhh = (const float*)d_in[10];
    const float* dw0 = (const float*)d_in[11];
    const float* db0 = (const float*)d_in[12];
    const float* dw1 = (const float*)d_in[13];
    const float* db1 = (const float*)d_in[14];
    float* out = (float*)d_out;

    gru_fused_kernel<<<256, NTH, 0, stream>>>(
        x, ew0, eb0, ew1, eb1, ew2, eb2, wih, whh, bih, bhh,
        dw0, db0, dw1, db1, out);
}